// Round 1
// baseline (1937.081 us; speedup 1.0000x reference)
//
#include <hip/hip_runtime.h>

#define EPSF 1e-8f
constexpr int ED = 4;   // nodes per wave in node kernel

typedef __attribute__((ext_vector_type(8))) short short8;
typedef __attribute__((ext_vector_type(4))) float float4v;

// ---- fp32 -> bf16 hi/lo split (RNE) ---------------------------------------
__device__ __forceinline__ unsigned bfhi_bits(float x) {
    unsigned u = __float_as_uint(x);
    return (u + 0x7fffu + ((u >> 16) & 1u)) >> 16;
}
__device__ __forceinline__ float bits2f(unsigned b) { return __uint_as_float(b << 16); }
__device__ __forceinline__ void split_bf(float x, unsigned short& h, unsigned short& l) {
    unsigned hb = bfhi_bits(x);
    h = (unsigned short)hb;
    l = (unsigned short)bfhi_bits(x - bits2f(hb));
}

// ---------------------------------------------------------------------------
// Pack W[NO][K] fp32 (row-major) into MFMA B-fragment order, bf16 hi/lo.
// ---------------------------------------------------------------------------
__global__ void pack_w(const float* __restrict__ W, unsigned short* __restrict__ hi,
                       unsigned short* __restrict__ lo, int NO, int K, int steps) {
    const int gid = blockIdx.x * 256 + threadIdx.x;
    const int total = (NO >> 4) * steps * 512;
    if (gid >= total) return;
    const int j = gid & 7, l = (gid >> 3) & 63, rest = gid >> 9;
    const int t = rest % steps, nt = rest / steps;
    const int n = nt * 16 + (l & 15);
    const int k = t * 32 + ((l >> 4) << 3) + j;
    const float x = (k < K) ? W[(size_t)n * K + k] : 0.f;
    unsigned short h, lw;
    split_bf(x, h, lw);
    hi[gid] = h; lo[gid] = lw;
}

// ---------------------------------------------------------------------------
// 3-pass split-bf16 MFMA K-loop (validated R4/R5).
// ---------------------------------------------------------------------------
template<int STEPS, int NTPW, int ASTR>
__device__ __forceinline__ void kloop(const unsigned short* PAh, const unsigned short* PAl,
    const unsigned short* __restrict__ wph, const unsigned short* __restrict__ wpl,
    float4v* acc, int lane, int wave)
{
    const int m = lane & 15, q = lane >> 4;
    for (int t = 0; t < STEPS; ++t) {
        const int k0 = t * 32 + q * 8;
        const short8 ah = *(const short8*)(PAh + m * ASTR + k0);
        const short8 al = *(const short8*)(PAl + m * ASTR + k0);
        #pragma unroll
        for (int i = 0; i < NTPW; ++i) {
            const int nt = wave * NTPW + i;
            const size_t off = ((size_t)(nt * STEPS + t) * 64 + lane) * 8;
            const short8 bh = *(const short8*)(wph + off);
            const short8 bl = *(const short8*)(wpl + off);
            acc[i] = __builtin_amdgcn_mfma_f32_16x16x32_bf16(ah, bh, acc[i], 0, 0, 0);
            acc[i] = __builtin_amdgcn_mfma_f32_16x16x32_bf16(al, bh, acc[i], 0, 0, 0);
            acc[i] = __builtin_amdgcn_mfma_f32_16x16x32_bf16(ah, bl, acc[i], 0, 0, 0);
        }
    }
}

// ---------------------------------------------------------------------------
// Edge kernel: 16 edges / block, 256 threads (4 waves).
// Strides: PA 352 shorts, PB 160 shorts, B0/B1 100 floats, B2 52 floats.
// B0 (fp32 V-concat) aliases the PB region (disjoint live ranges).
// Thread map for elementwise phases: e = tid&15, q16 = tid>>4  (pow2, no div).
// Aggregation is fp64 atomics: order-invariant to fp32 precision, so graph
// replays are deterministic (post-timing check == first check).
// ---------------------------------------------------------------------------
constexpr int SA  = 352;
constexpr int SBs = 160;
constexpr int SB1 = 100;
constexpr int SB2 = 52;

__global__ __launch_bounds__(256)
void edge_kernel(const float* __restrict__ s, const float* __restrict__ v,
                 const int* __restrict__ eidx,
                 const float* __restrict__ es, const float* __restrict__ ev,
                 const float* __restrict__ m1_wh, const float* __restrict__ m1_wsb,
                 const float* __restrict__ m1_wv,
                 const float* __restrict__ m2_wh, const float* __restrict__ m2_wsb,
                 const float* __restrict__ m2_wv,
                 const float* __restrict__ m3_wh, const float* __restrict__ m3_wsb,
                 const float* __restrict__ m3_wv,
                 const unsigned short* __restrict__ p1h, const unsigned short* __restrict__ p1l,
                 const unsigned short* __restrict__ p2h, const unsigned short* __restrict__ p2l,
                 const unsigned short* __restrict__ p3h, const unsigned short* __restrict__ p3l,
                 double* __restrict__ agg_s, double* __restrict__ agg_v,
                 float* __restrict__ cnt, int E)
{
    __shared__ __align__(16) unsigned short PAh[16 * SA], PAl[16 * SA];
    __shared__ __align__(16) unsigned short PBmem[2 * 16 * SBs];
    __shared__ __align__(16) float B1[16 * SB1];
    __shared__ __align__(16) float B2[16 * SB2];
    __shared__ int ssrc[16], sgd[16], sdst[16], seid[16];

    unsigned short* PBh = PBmem;
    unsigned short* PBl = PBmem + 16 * SBs;
    float* B0 = (float*)PBmem;          // aliases PB: dead before PB is written

    const int tid = threadIdx.x, lane = tid & 63, wave = tid >> 6;
    const int e = tid & 15, q16 = tid >> 4;
    const int e0 = blockIdx.x * 16;

    // E1: indices
    if (tid < 16) {
        const int eg = e0 + tid;
        const bool ok = (eg < E);
        const int ee = ok ? eg : (E - 1);
        seid[tid] = ee;
        ssrc[tid] = eidx[ee];
        const int d = eidx[E + ee];
        sgd[tid] = d;
        sdst[tid] = ok ? d : -1;
    }
    __syncthreads();

    // E2a: S-concat gather -> PA[0,288) as short8 b128 writes (8 floats/task)
    #pragma unroll
    for (int it = 0; it < 3; ++it) {
        const int c = q16 + 16 * it;
        if (c < 36) {
            const float* srcp; int col;
            if (c < 16)      { srcp = s  + (size_t)ssrc[e] * 128 + 8 * c;       col = 8 * c; }
            else if (c < 20) { srcp = es + (size_t)seid[e] * 32 + 8 * (c - 16); col = 128 + 8 * (c - 16); }
            else             { srcp = s  + (size_t)sgd[e]  * 128 + 8 * (c - 20); col = 160 + 8 * (c - 20); }
            const float4 x = ((const float4*)srcp)[0];
            const float4 y = ((const float4*)srcp)[1];
            short8 hv, lv; unsigned short h, l;
            split_bf(x.x, h, l); hv[0] = h; lv[0] = l;
            split_bf(x.y, h, l); hv[1] = h; lv[1] = l;
            split_bf(x.z, h, l); hv[2] = h; lv[2] = l;
            split_bf(x.w, h, l); hv[3] = h; lv[3] = l;
            split_bf(y.x, h, l); hv[4] = h; lv[4] = l;
            split_bf(y.y, h, l); hv[5] = h; lv[5] = l;
            split_bf(y.z, h, l); hv[6] = h; lv[6] = l;
            split_bf(y.w, h, l); hv[7] = h; lv[7] = l;
            *(short8*)(PAh + e * SA + col) = hv;
            *(short8*)(PAl + e * SA + col) = lv;
        }
    }
    // zero-pad PA cols [320,352)  (col 320 is later overwritten by vn1[32] after the barrier)
    #pragma unroll
    for (int it = 0; it < 2; ++it) {
        const int col = 320 + q16 + 16 * it;
        PAh[e * SA + col] = 0; PAl[e * SA + col] = 0;
    }
    // E2b: V-concat gather -> B0 (fp32, cols c*3+t, 99 used)
    {
        if (q16 < 12) {
            const float4 x = ((const float4*)(v + (size_t)ssrc[e] * 48))[q16];
            *(float4*)(B0 + e * SB1 + 4 * q16) = x;
        } else if (q16 == 12) {
            const float* qv = ev + (size_t)seid[e] * 3;
            float* p = B0 + e * SB1 + 48;
            p[0] = qv[0]; p[1] = qv[1]; p[2] = qv[2];
        }
        if (q16 < 12) {
            const float4 x = ((const float4*)(v + (size_t)sgd[e] * 48))[q16];
            float* p = B0 + e * SB1 + 51 + 4 * q16;
            p[0] = x.x; p[1] = x.y; p[2] = x.z; p[3] = x.w;
        }
    }
    __syncthreads();

    // E3+E4 fused: vh1 = m1_wh @ Vcat -> B1; vn1 -> PA[288,321)
    #pragma unroll
    for (int it = 0; it < 3; ++it) {
        const int h = q16 + 16 * it;
        if (h < 33) {
            const float* wrow = m1_wh + h * 33;
            const float* vb = B0 + e * SB1;
            float a0 = 0.f, a1 = 0.f, a2 = 0.f;
            for (int c = 0; c < 33; ++c) {
                const float w = wrow[c];
                a0 = fmaf(vb[c * 3 + 0], w, a0);
                a1 = fmaf(vb[c * 3 + 1], w, a1);
                a2 = fmaf(vb[c * 3 + 2], w, a2);
            }
            float* o = B1 + e * SB1 + h * 3;
            o[0] = a0; o[1] = a1; o[2] = a2;
            const float vn = sqrtf(fmaxf(a0 * a0 + a1 * a1 + a2 * a2, EPSF));
            unsigned short hh, ll; split_bf(vn, hh, ll);
            PAh[e * SA + 288 + h] = hh; PAl[e * SA + 288 + h] = ll;
        }
    }
    __syncthreads();

    // E5: m1 MFMA (K=352) -> relu -> PB[0,128); vout1 -> B2
    {
        float4v acc[2] = {{0,0,0,0},{0,0,0,0}};
        kloop<11, 2, SA>(PAh, PAl, p1h, p1l, acc, lane, wave);
        const int q = lane >> 4;
        #pragma unroll
        for (int i = 0; i < 2; ++i) {
            const int n = (wave * 2 + i) * 16 + (lane & 15);
            const float bias = m1_wsb[n];
            #pragma unroll
            for (int r = 0; r < 4; ++r) {
                const int m = q * 4 + r;
                const float x = fmaxf(acc[i][r] + bias, 0.f);
                unsigned short h, l; split_bf(x, h, l);
                PBh[m * SBs + n] = h; PBl[m * SBs + n] = l;
            }
        }
    }
    {   // vout1: o = q16 (VO=16), all threads active
        const int o = q16;
        float a0 = 0.f, a1 = 0.f, a2 = 0.f;
        for (int h = 0; h < 33; ++h) {
            const float w = m1_wv[o * 33 + h];
            const float* p = B1 + e * SB1 + h * 3;
            a0 = fmaf(p[0], w, a0); a1 = fmaf(p[1], w, a1); a2 = fmaf(p[2], w, a2);
        }
        const float nrm = sqrtf(fmaxf(a0 * a0 + a1 * a1 + a2 * a2, EPSF));
        const float sg = 1.f / (1.f + __expf(-nrm));
        float* p2 = B2 + e * SB2 + o * 3;
        p2[0] = a0 * sg; p2[1] = a1 * sg; p2[2] = a2 * sg;
    }
    __syncthreads();

    // E6+E7 fused: vh2 -> B1; vn2 -> PB[128,144); zero PB[144,160)
    {
        const int h = q16;
        float a0 = 0.f, a1 = 0.f, a2 = 0.f;
        for (int c = 0; c < 16; ++c) {
            const float w = m2_wh[h * 16 + c];
            const float* p = B2 + e * SB2 + c * 3;
            a0 = fmaf(p[0], w, a0); a1 = fmaf(p[1], w, a1); a2 = fmaf(p[2], w, a2);
        }
        float* o = B1 + e * SB1 + h * 3;
        o[0] = a0; o[1] = a1; o[2] = a2;
        const float vn = sqrtf(fmaxf(a0 * a0 + a1 * a1 + a2 * a2, EPSF));
        unsigned short hh, ll; split_bf(vn, hh, ll);
        PBh[e * SBs + 128 + h] = hh; PBl[e * SBs + 128 + h] = ll;
        PBh[e * SBs + 144 + h] = 0;  PBl[e * SBs + 144 + h] = 0;
    }
    __syncthreads();

    // E8: m2 MFMA (K=160) -> relu -> PA[0,128); vout2 -> B2
    {
        float4v acc[2] = {{0,0,0,0},{0,0,0,0}};
        kloop<5, 2, SBs>(PBh, PBl, p2h, p2l, acc, lane, wave);
        const int q = lane >> 4;
        #pragma unroll
        for (int i = 0; i < 2; ++i) {
            const int n = (wave * 2 + i) * 16 + (lane & 15);
            const float bias = m2_wsb[n];
            #pragma unroll
            for (int r = 0; r < 4; ++r) {
                const int m = q * 4 + r;
                const float x = fmaxf(acc[i][r] + bias, 0.f);
                unsigned short h, l; split_bf(x, h, l);
                PAh[m * SA + n] = h; PAl[m * SA + n] = l;
            }
        }
    }
    {   // vout2
        const int o = q16;
        float a0 = 0.f, a1 = 0.f, a2 = 0.f;
        for (int h = 0; h < 16; ++h) {
            const float w = m2_wv[o * 16 + h];
            const float* p = B1 + e * SB1 + h * 3;
            a0 = fmaf(p[0], w, a0); a1 = fmaf(p[1], w, a1); a2 = fmaf(p[2], w, a2);
        }
        const float nrm = sqrtf(fmaxf(a0 * a0 + a1 * a1 + a2 * a2, EPSF));
        const float sg = 1.f / (1.f + __expf(-nrm));
        float* p2 = B2 + e * SB2 + o * 3;
        p2[0] = a0 * sg; p2[1] = a1 * sg; p2[2] = a2 * sg;
    }
    __syncthreads();

    // E9+E10 fused: vh3 -> B1; vn3 -> PA[128,144); zero PA[144,160)
    {
        const int h = q16;
        float a0 = 0.f, a1 = 0.f, a2 = 0.f;
        for (int c = 0; c < 16; ++c) {
            const float w = m3_wh[h * 16 + c];
            const float* p = B2 + e * SB2 + c * 3;
            a0 = fmaf(p[0], w, a0); a1 = fmaf(p[1], w, a1); a2 = fmaf(p[2], w, a2);
        }
        float* o = B1 + e * SB1 + h * 3;
        o[0] = a0; o[1] = a1; o[2] = a2;
        const float vn = sqrtf(fmaxf(a0 * a0 + a1 * a1 + a2 * a2, EPSF));
        unsigned short hh, ll; split_bf(vn, hh, ll);
        PAh[e * SA + 128 + h] = hh; PAl[e * SA + 128 + h] = ll;
        PAh[e * SA + 144 + h] = 0;  PAl[e * SA + 144 + h] = 0;
    }
    __syncthreads();

    // E11: m3 MFMA (K=160, no act) + vout3 (no act) -> B2
    float4v acc3[2] = {{0,0,0,0},{0,0,0,0}};
    kloop<5, 2, SA>(PAh, PAl, p3h, p3l, acc3, lane, wave);
    {
        const int o = q16;
        float a0 = 0.f, a1 = 0.f, a2 = 0.f;
        for (int h = 0; h < 16; ++h) {
            const float w = m3_wv[o * 16 + h];
            const float* p = B1 + e * SB1 + h * 3;
            a0 = fmaf(p[0], w, a0); a1 = fmaf(p[1], w, a1); a2 = fmaf(p[2], w, a2);
        }
        float* p2 = B2 + e * SB2 + o * 3;
        p2[0] = a0; p2[1] = a1; p2[2] = a2;
    }
    __syncthreads();

    // E12: scatter-add (fp64 atomics -> order-invariant aggregation)
    {
        const int q = lane >> 4;
        #pragma unroll
        for (int i = 0; i < 2; ++i) {
            const int n = (wave * 2 + i) * 16 + (lane & 15);
            const float bias = m3_wsb[n];
            #pragma unroll
            for (int r = 0; r < 4; ++r) {
                const int m = q * 4 + r;
                const int d = sdst[m];
                if (d >= 0) atomicAdd(&agg_s[(size_t)d * 128 + n], (double)(acc3[i][r] + bias));
            }
        }
    }
    #pragma unroll
    for (int it = 0; it < 3; ++it) {
        const int j = q16 + 16 * it;     // j < 48 exactly
        const int d = sdst[e];
        if (d >= 0) atomicAdd(&agg_v[(size_t)d * 48 + j], (double)B2[e * SB2 + j]);
    }
    if (tid < 16 && sdst[tid] >= 0) atomicAdd(&cnt[sdst[tid]], 1.0f);
}

// ===========================================================================
// R3/R5's proven fp32-VALU node path (verbatim)
// ===========================================================================
template<int VI, int H, int SIcat, int KP, int SO, int VO, bool ACT,
         int SSTR, int VSTR, int HSTR, int SOSTR, int VOSTR>
__device__ __forceinline__ void gvp4(
    float* S, const float* V, float* VH, float* SOb, float* VOb,
    const float* __restrict__ wh, const float* __restrict__ wswP,
    const float* __restrict__ wsb, const float* __restrict__ wv, int lane)
{
    static_assert(SO % 64 == 0 && KP % 4 == 0, "shape");
    for (int idx = lane; idx < H * 3; idx += 64) {
        const int h = idx / 3, t = idx - h * 3;
        const float* w = wh + h * VI;
        float acc[ED] = {0.f, 0.f, 0.f, 0.f};
        for (int c = 0; c < VI; ++c) {
            const float wc = w[c];
            #pragma unroll
            for (int e = 0; e < ED; ++e) acc[e] = fmaf(V[e * VSTR + c * 3 + t], wc, acc[e]);
        }
        #pragma unroll
        for (int e = 0; e < ED; ++e) VH[e * HSTR + idx] = acc[e];
    }
    __syncthreads();
    for (int h = lane; h < H; h += 64) {
        #pragma unroll
        for (int e = 0; e < ED; ++e) {
            const float a = VH[e * HSTR + h * 3 + 0], b = VH[e * HSTR + h * 3 + 1],
                        c = VH[e * HSTR + h * 3 + 2];
            S[e * SSTR + SIcat + h] = sqrtf(fmaxf(a * a + b * b + c * c, EPSF));
        }
    }
    __syncthreads();
    constexpr int OF = SO / 64;
    {
        float acc[OF][ED];
        #pragma unroll
        for (int of = 0; of < OF; ++of) {
            const float bias = wsb[lane + of * 64];
            #pragma unroll
            for (int e = 0; e < ED; ++e) acc[of][e] = bias;
        }
        for (int k = 0; k < KP; k += 4) {
            float4 sv[ED];
            #pragma unroll
            for (int e = 0; e < ED; ++e) sv[e] = *(const float4*)&S[e * SSTR + k];
            #pragma unroll
            for (int of = 0; of < OF; ++of) {
                const float4 w = *(const float4*)&wswP[(size_t)(lane + of * 64) * KP + k];
                #pragma unroll
                for (int e = 0; e < ED; ++e) {
                    acc[of][e] = fmaf(w.x, sv[e].x, acc[of][e]);
                    acc[of][e] = fmaf(w.y, sv[e].y, acc[of][e]);
                    acc[of][e] = fmaf(w.z, sv[e].z, acc[of][e]);
                    acc[of][e] = fmaf(w.w, sv[e].w, acc[of][e]);
                }
            }
        }
        #pragma unroll
        for (int of = 0; of < OF; ++of)
            #pragma unroll
            for (int e = 0; e < ED; ++e) {
                float a = acc[of][e];
                if (ACT) a = fmaxf(a, 0.f);
                SOb[e * SOSTR + lane + of * 64] = a;
            }
    }
    for (int idx = lane; idx < VO * 3; idx += 64) {
        const int o = idx / 3, t = idx - o * 3;
        const float* w = wv + o * H;
        float acc[ED] = {0.f, 0.f, 0.f, 0.f};
        for (int h = 0; h < H; ++h) {
            const float wc = w[h];
            #pragma unroll
            for (int e = 0; e < ED; ++e) acc[e] = fmaf(VH[e * HSTR + h * 3 + t], wc, acc[e]);
        }
        #pragma unroll
        for (int e = 0; e < ED; ++e) VOb[e * VOSTR + idx] = acc[e];
    }
    __syncthreads();
    if (ACT) {
        for (int o = lane; o < VO; o += 64) {
            #pragma unroll
            for (int e = 0; e < ED; ++e) {
                float* p = VOb + e * VOSTR + o * 3;
                const float a = p[0], b = p[1], c = p[2];
                const float nrm = sqrtf(fmaxf(a * a + b * b + c * c, EPSF));
                const float sg = 1.f / (1.f + __expf(-nrm));
                p[0] = a * sg; p[1] = b * sg; p[2] = c * sg;
            }
        }
        __syncthreads();
    }
}

template<int SSTR, int VSTR>
__device__ __forceinline__ void layer_norm4(float* S, float* V,
    const float* __restrict__ g, const float* __restrict__ b, float* red, int lane)
{
    #pragma unroll
    for (int e = 0; e < ED; ++e) {
        float x0 = S[e * SSTR + lane], x1 = S[e * SSTR + 64 + lane];
        float sum = x0 + x1;
        #pragma unroll
        for (int off = 32; off > 0; off >>= 1) sum += __shfl_xor(sum, off, 64);
        const float mu = sum * (1.f / 128.f);
        const float d0 = x0 - mu, d1 = x1 - mu;
        float vs = d0 * d0 + d1 * d1;
        #pragma unroll
        for (int off = 32; off > 0; off >>= 1) vs += __shfl_xor(vs, off, 64);
        const float rstd = rsqrtf(vs * (1.f / 128.f) + 1e-5f);
        S[e * SSTR + lane]      = d0 * rstd * g[lane]      + b[lane];
        S[e * SSTR + 64 + lane] = d1 * rstd * g[lane + 64] + b[lane + 64];

        if (lane < 16) {
            const float a = V[e * VSTR + lane * 3], bb = V[e * VSTR + lane * 3 + 1],
                        cc = V[e * VSTR + lane * 3 + 2];
            const float vn = fmaxf(a * a + bb * bb + cc * cc, EPSF);
            red[lane]      = vn;
            red[16 + lane] = (vn > 2.f * EPSF) ? 1.f : 0.f;
        }
        __syncthreads();
        float sn = 0.f, sm = 0.f;
        #pragma unroll
        for (int i = 0; i < 16; ++i) { sn += red[i] * red[16 + i]; sm += red[16 + i]; }
        const float rvm = rsqrtf(sn / (EPSF + sm) + EPSF);
        if (lane < 48) V[e * VSTR + lane] = red[16 + lane / 3] * V[e * VSTR + lane] * rvm;
        __syncthreads();
    }
}

__global__ __launch_bounds__(128)
void node_kernel(const float* __restrict__ s, const float* __restrict__ v,
                 const float* __restrict__ f1_wh, const float* __restrict__ f1_wsw,
                 const float* __restrict__ f1_wsb, const float* __restrict__ f1_wv,
                 const float* __restrict__ f2_wh, const float* __restrict__ f2_wsw,
                 const float* __restrict__ f2_wsb, const float* __restrict__ f2_wv,
                 const float* __restrict__ ln0_g, const float* __restrict__ ln0_b,
                 const float* __restrict__ ln1_g, const float* __restrict__ ln1_b,
                 const double* __restrict__ agg_s, const double* __restrict__ agg_v,
                 const float* __restrict__ cnt,
                 float* __restrict__ out, int N)
{
    __shared__ __align__(16) float nsm[2 * 4608];
    const int wave = threadIdx.x >> 6, lane = threadIdx.x & 63;
    float* S1  = nsm + wave * 4608;
    float* V1  = S1 + 640;
    float* FS  = S1 + 832;
    float* FV  = S1 + 3008;
    float* VHb = S1 + 3392;
    float* OS  = S1 + 3776;
    float* OV  = S1 + 4288;
    float* red = S1 + 4480;

    const int n0 = (blockIdx.x * 2 + wave) * ED;
    bool oks[ED];
    #pragma unroll
    for (int e = 0; e < ED; ++e) {
        const int ng = n0 + e;
        oks[e] = (ng < N);
        const int n = oks[e] ? ng : (N - 1);
        const double inv = 1.0 / (double)fmaxf(cnt[n], 1.f);
        if (lane < 32) {
            const float4 a = ((const float4*)(s + (size_t)n * 128))[lane];
            const double2 b0 = ((const double2*)(agg_s + (size_t)n * 128))[2 * lane];
            const double2 b1 = ((const double2*)(agg_s + (size_t)n * 128))[2 * lane + 1];
            float4 r;
            r.x = (float)((double)a.x + b0.x * inv);
            r.y = (float)((double)a.y + b0.y * inv);
            r.z = (float)((double)a.z + b1.x * inv);
            r.w = (float)((double)a.w + b1.y * inv);
            ((float4*)(S1 + e * 160))[lane] = r;
        }
        if (lane < 12) {
            const float4 a = ((const float4*)(v + (size_t)n * 48))[lane];
            const double2 b0 = ((const double2*)(agg_v + (size_t)n * 48))[2 * lane];
            const double2 b1 = ((const double2*)(agg_v + (size_t)n * 48))[2 * lane + 1];
            float4 r;
            r.x = (float)((double)a.x + b0.x * inv);
            r.y = (float)((double)a.y + b0.y * inv);
            r.z = (float)((double)a.z + b1.x * inv);
            r.w = (float)((double)a.w + b1.y * inv);
            ((float4*)(V1 + e * 48))[lane] = r;
        }
    }
    __syncthreads();

    layer_norm4<160, 48>(S1, V1, ln0_g, ln0_b, red, lane);

    gvp4<16, 32, 128, 160, 512, 32, true, 160, 48, 96, 544, 96>(
        S1, V1, VHb, FS, FV, f1_wh, f1_wsw, f1_wsb, f1_wv, lane);
    gvp4<32, 32, 512, 544, 128, 16, false, 544, 96, 96, 128, 48>(
        FS, FV, VHb, OS, OV, f2_wh, f2_wsw, f2_wsb, f2_wv, lane);

    #pragma unroll
    for (int e = 0; e < ED; ++e) {
        for (int i = lane; i < 128; i += 64) OS[e * 128 + i] += S1[e * 160 + i];
        if (lane < 48) OV[e * 48 + lane] += V1[e * 48 + lane];
    }
    __syncthreads();

    layer_norm4<128, 48>(OS, OV, ln1_g, ln1_b, red, lane);

    #pragma unroll
    for (int e = 0; e < ED; ++e) {
        if (!oks[e]) continue;
        const int n = n0 + e;
        if (lane < 32)
            ((float4*)(out + (size_t)n * 128))[lane] = ((const float4*)(OS + e * 128))[lane];
        if (lane < 12)
            ((float4*)(out + (size_t)N * 128 + (size_t)n * 48))[lane] =
                ((const float4*)(OV + e * 48))[lane];
    }
}

// ---------------------------------------------------------------------------
extern "C" void kernel_launch(void* const* d_in, const int* in_sizes, int n_in,
                              void* d_out, int out_size, void* d_ws, size_t ws_size,
                              hipStream_t stream)
{
    const float* s    = (const float*)d_in[0];
    const float* v    = (const float*)d_in[1];
    const int*   eidx = (const int*)d_in[2];
    const float* es   = (const float*)d_in[3];
    const float* ev   = (const float*)d_in[4];
    const float* m1_wh = (const float*)d_in[5];
    const float* m1_wsw = (const float*)d_in[6];
    const float* m1_wsb = (const float*)d_in[7];
    const float* m1_wv = (const float*)d_in[8];
    const float* m2_wh = (const float*)d_in[9];
    const float* m2_wsw = (const float*)d_in[10];
    const float* m2_wsb = (const float*)d_in[11];
    const float* m2_wv = (const float*)d_in[12];
    const float* m3_wh = (const float*)d_in[13];
    const float* m3_wsw = (const float*)d_in[14];
    const float* m3_wsb = (const float*)d_in[15];
    const float* m3_wv = (const float*)d_in[16];
    const float* f1_wh = (const float*)d_in[17];
    const float* f1_wsw = (const float*)d_in[18];
    const float* f1_wsb = (const float*)d_in[19];
    const float* f1_wv = (const float*)d_in[20];
    const float* f2_wh = (const float*)d_in[21];
    const float* f2_wsw = (const float*)d_in[22];
    const float* f2_wsb = (const float*)d_in[23];
    const float* f2_wv = (const float*)d_in[24];
    const float* ln0_g = (const float*)d_in[25];
    const float* ln0_b = (const float*)d_in[26];
    const float* ln1_g = (const float*)d_in[27];
    const float* ln1_b = (const float*)d_in[28];

    const int N = in_sizes[0] / 128;
    const int E = in_sizes[2] / 2;

    double* agg_s = (double*)d_ws;                     // N*128 f64
    double* agg_v = agg_s + (size_t)N * 128;           // N*48  f64
    float* cnt    = (float*)(agg_v + (size_t)N * 48);  // N     f32
    unsigned short* pk =
        (unsigned short*)(((uintptr_t)(cnt + N) + 15) & ~(uintptr_t)15);
    const int S_M1 = 45056, S_M23 = 20480;
    unsigned short* p1h = pk;            unsigned short* p1l = p1h + S_M1;
    unsigned short* p2h = p1l + S_M1;    unsigned short* p2l = p2h + S_M23;
    unsigned short* p3h = p2l + S_M23;   unsigned short* p3l = p3h + S_M23;

    hipMemsetAsync(d_ws, 0,
                   (size_t)N * 176 * sizeof(double) + (size_t)N * sizeof(float),
                   stream);

    pack_w<<<dim3((S_M1  + 255) / 256), dim3(256), 0, stream>>>(m1_wsw, p1h, p1l, 128, 321, 11);
    pack_w<<<dim3((S_M23 + 255) / 256), dim3(256), 0, stream>>>(m2_wsw, p2h, p2l, 128, 144, 5);
    pack_w<<<dim3((S_M23 + 255) / 256), dim3(256), 0, stream>>>(m3_wsw, p3h, p3l, 128, 144, 5);

    edge_kernel<<<dim3((E + 15) / 16), dim3(256), 0, stream>>>(
        s, v, eidx, es, ev,
        m1_wh, m1_wsb, m1_wv,
        m2_wh, m2_wsb, m2_wv,
        m3_wh, m3_wsb, m3_wv,
        p1h, p1l, p2h, p2l, p3h, p3l,
        agg_s, agg_v, cnt, E);

    node_kernel<<<dim3((N + 7) / 8), dim3(128), 0, stream>>>(
        s, v,
        f1_wh, f1_wsw, f1_wsb, f1_wv,
        f2_wh, f2_wsw, f2_wsb, f2_wv,
        ln0_g, ln0_b, ln1_g, ln1_b,
        agg_s, agg_v, cnt,
        (float*)d_out, N);
}